// Round 7
// baseline (86577.026 us; speedup 1.0000x reference)
//
#include <hip/hip_runtime.h>
#include <cstddef>
#include <cstdint>
#include <cmath>

#define NBLK 256
#define NTHR 1024

// ---- dynamic LDS float offsets ----
#define L_WIH   0        // 6 rows x 1156 (pad): s = rh*3+gate, col 2blk+rh
#define L_WOUT  6936     // 8 rows x 1028 (pad): score rows 8blk..8blk+7
#define L_WT    15160    // 2 rows x 516 (pad): W_attn^T rows 2blk,2blk+1
#define L_VVS   16192    // 576: vv staged as [l*18 + e] (32 l-groups of 16)
#define L_LSE   16768    // 2: lse, amax
#define L_SL    16770    // 16: per-wave s_loc partials
#define L_FA    16792    // 16 x 578: flash rowsets [w][l*18+e]
#define L_TOT   26040    // floats = 101.7 KiB

// ---- ws float offsets ----
#define WS_HDN   1088     // [64][512]
#define WS_VV    33856    // [64][512]
#define WS_SC    66624    // [64][2048]
#define WS_PACC  197696   // [2][64][512]
#define WS_PS    263232   // [2][64]
#define WS_EMB   263360   // [64][128]
#define WS_PART  271552   // [64][256][4] {m, se, idxf, pad}

__device__ __forceinline__ float dot4(float4 a, float4 b) {
    return a.x*b.x + a.y*b.y + a.z*b.z + a.w*b.w;
}

// sc1 (agent-scope) stores: visible at the device coherence point.
__device__ __forceinline__ void st1(float* p, float v) {
    __hip_atomic_store(p, v, __ATOMIC_RELAXED, __HIP_MEMORY_SCOPE_AGENT);
}
__device__ __forceinline__ void st2(float* p, float a, float b) {
    union { unsigned long long u; float2 f; } c; c.f = make_float2(a, b);
    __hip_atomic_store((unsigned long long*)p, c.u,
        __ATOMIC_RELAXED, __HIP_MEMORY_SCOPE_AGENT);
}

// Hierarchical grid barrier (R4/R5-proven): 32 groups of 8 -> root -> gen,
// all monotonic+relaxed; exit does an agent-scope ACQUIRE (cache invalidate)
// so subsequent PLAIN cached loads see sc1 stores.
__device__ __forceinline__ void gridbar(unsigned* bar, unsigned iter) {
    asm volatile("s_waitcnt vmcnt(0) lgkmcnt(0)" ::: "memory");
    __syncthreads();
    if (threadIdx.x == 0) {
        const unsigned g = blockIdx.x >> 3;
        unsigned p = __hip_atomic_fetch_add(bar + 64 + g * 32, 1u,
                        __ATOMIC_RELAXED, __HIP_MEMORY_SCOPE_AGENT);
        if (p == iter * 8u - 1u) {
            unsigned rp = __hip_atomic_fetch_add(bar, 1u,
                        __ATOMIC_RELAXED, __HIP_MEMORY_SCOPE_AGENT);
            if (rp == iter * 32u - 1u)
                __hip_atomic_store(bar + 32, iter, __ATOMIC_RELAXED,
                                   __HIP_MEMORY_SCOPE_AGENT);
        }
        while (__hip_atomic_load(bar + 32, __ATOMIC_RELAXED,
                                 __HIP_MEMORY_SCOPE_AGENT) < iter)
            __builtin_amdgcn_s_sleep(1);
    }
    __syncthreads();
    (void)__hip_atomic_load(bar + 32, __ATOMIC_ACQUIRE, __HIP_MEMORY_SCOPE_AGENT);
    asm volatile("" ::: "memory");
}

__global__ __launch_bounds__(NTHR, 4) void nmt_fused(
    const float* __restrict__ enc, const int* __restrict__ mask,
    const float* __restrict__ embTab, const float* __restrict__ Wih,
    const float* __restrict__ bih, const float* __restrict__ bhh,
    const float* __restrict__ Wa, const float* __restrict__ Wout,
    const float* __restrict__ bout, float* __restrict__ out,
    float* __restrict__ ws)
{
    extern __shared__ float smem[];

    const int blk = blockIdx.x;
    const int tid = threadIdx.x;

    unsigned* bar = (unsigned*)ws;
    float* hdnw = ws + WS_HDN;
    float* vvw  = ws + WS_VV;
    float* scw  = ws + WS_SC;
    float* pacc = ws + WS_PACC;
    float* ps   = ws + WS_PS;
    float* embw = ws + WS_EMB;
    float* partw= ws + WS_PART;

    unsigned bi = 0;

    // ---------------- prologue: weights -> LDS (padded rows) ----------------
    {
        #pragma unroll
        for (int s = 0; s < 6; ++s) {
            const int col = 2 * blk + (s >= 3 ? 1 : 0);
            const int gate = s % 3;
            const int grow = (gate == 0) ? col : (gate == 1) ? 1024 + col : 1536 + col;
            for (int off = tid; off < 1152; off += NTHR)
                smem[L_WIH + s * 1156 + off] = Wih[(size_t)grow * 1152 + off];
        }
        #pragma unroll
        for (int s = 0; s < 8; ++s)
            for (int off = tid; off < 1024; off += NTHR)
                smem[L_WOUT + s * 1028 + off] = Wout[(size_t)(8 * blk + s) * 1024 + off];
        #pragma unroll
        for (int s = 0; s < 2; ++s)
            if (tid < 512)
                smem[L_WT + s * 516 + tid] = Wa[(size_t)tid * 512 + (2 * blk + s)];
    }
    // thread roles (P1/P2)
    const int q  = tid & 15;          // k-split 16
    const int rh = (tid >> 4) & 1;    // row-half
    const int bl = tid >> 5;          // 32 groups x 2 batches

    // P1 biases: col = 2blk + rh
    const int colP1 = 2 * blk + rh;
    const float biB = bih[colP1]        + bhh[colP1];
    const float bgB = bih[1024 + colP1] + bhh[1024 + colP1];
    const float boB = bih[1536 + colP1] + bhh[1536 + colP1];
    // P2 biases: rows 8blk + rh*4 + rr
    float bo_r[4];
    #pragma unroll
    for (int rr = 0; rr < 4; ++rr) bo_r[rr] = bout[8 * blk + rh * 4 + rr];

    // state init (blocks 0..63): ctx0 -> pacc slot1, ps slot1 = 1, emb = 0
    if (blk < 64) {
        const int b = blk;
        int* ism = (int*)(smem + L_FA);
        ism[tid] = (tid < 512) ? mask[b * 512 + tid] : 0;
        __syncthreads();
        for (int off = 512; off; off >>= 1) {
            if (tid < off) ism[tid] += ism[tid + off];
            __syncthreads();
        }
        int tl = ism[0] - 1;
        if (tl < 0) tl = 0;
        if (tid < 512)
            st1(pacc + 32768 + b * 512 + tid, enc[((size_t)(b * 512 + tl)) * 512 + tid]);
        if (tid == 0) st1(ps + 64 + b, 1.f);
        if (tid < 128) st1(embw + b * 128 + tid, 0.f);
        __syncthreads();
    }
    gridbar(bar, ++bi);

    // ---------------- main loop ----------------
    for (int t = 0; t < 512; ++t) {
        const int cur = t & 1;
        float* paccC = pacc + cur * 32768;
        const float* paccP = pacc + (cur ^ 1) * 32768;
        float* psC = ps + cur * 64;
        const float* psP = ps + (cur ^ 1) * 64;

        // ===== P1: gates GEMM (LDS weights) + LSTM -> hdn =====
        {
            // zero cur-slot accumulators for P3's atomics
            if (tid < 128) st1(paccC + blk * 128 + tid, 0.f);
            if (blk == 0 && tid < 64) st1(psC + tid, 0.f);

            float inv[2];
            #pragma unroll
            for (int i = 0; i < 2; ++i) {
                float sden = psP[2 * bl + i];
                inv[i] = (sden != 0.f) ? 1.f / sden : 0.f;
            }

            float4 xA[2], xB[2], nA[2], nB[2];
            // preload c = 0 (emb)
            #pragma unroll
            for (int i = 0; i < 2; ++i) {
                const float* src = embw + (2 * bl + i) * 128 + q * 8;
                xA[i] = *(const float4*)src;
                xB[i] = *(const float4*)(src + 4);
            }

            float acc[3][2];
            #pragma unroll
            for (int gq = 0; gq < 3; ++gq) { acc[gq][0] = 0.f; acc[gq][1] = 0.f; }

            #pragma unroll
            for (int c = 0; c < 9; ++c) {
                // prefetch c+1
                if (c < 8) {
                    const int cn = c + 1;
                    #pragma unroll
                    for (int i = 0; i < 2; ++i) {
                        const int b = 2 * bl + i;
                        const float* src;
                        if (cn <= 4) src = paccP + b * 512 + (cn - 1) * 128 + q * 8;
                        else         src = enc + ((size_t)(b * 512 + t)) * 512
                                               + (cn - 5) * 128 + q * 8;
                        float4 a = *(const float4*)src;
                        float4 bq = *(const float4*)(src + 4);
                        if (cn <= 4) {
                            a.x *= inv[i]; a.y *= inv[i]; a.z *= inv[i]; a.w *= inv[i];
                            bq.x *= inv[i]; bq.y *= inv[i]; bq.z *= inv[i]; bq.w *= inv[i];
                        }
                        nA[i] = a; nB[i] = bq;
                    }
                }
                // compute c
                #pragma unroll
                for (int gq = 0; gq < 3; ++gq) {
                    const float* wl = smem + L_WIH + (rh * 3 + gq) * 1156 + c * 128 + q * 8;
                    float4 w0 = *(const float4*)wl;
                    float4 w1 = *(const float4*)(wl + 4);
                    acc[gq][0] += dot4(w0, xA[0]) + dot4(w1, xB[0]);
                    acc[gq][1] += dot4(w0, xA[1]) + dot4(w1, xB[1]);
                }
                if (c < 8) {
                    xA[0] = nA[0]; xA[1] = nA[1];
                    xB[0] = nB[0]; xB[1] = nB[1];
                }
            }
            #pragma unroll
            for (int gq = 0; gq < 3; ++gq)
                #pragma unroll
                for (int i = 0; i < 2; ++i) {
                    #pragma unroll
                    for (int off = 1; off < 16; off <<= 1)
                        acc[gq][i] += __shfl_xor(acc[gq][i], off);
                }
            if (q == 0) {
                #pragma unroll
                for (int i = 0; i < 2; ++i) {
                    float ig = acc[0][i] + biB;
                    float gg = acc[1][i] + bgB;
                    float og = acc[2][i] + boB;
                    float cv = (1.f / (1.f + expf(-ig))) * tanhf(gg);
                    float hv = (1.f / (1.f + expf(-og))) * tanhf(cv);
                    st1(hdnw + (2 * bl + i) * 512 + colP1, hv);
                }
            }
        }
        gridbar(bar, ++bi);

        // ===== P2: scores (4 rows/half) + vv (1 row/half) =====
        {
            float inv[2];
            #pragma unroll
            for (int i = 0; i < 2; ++i) {
                float sden = psP[2 * bl + i];
                inv[i] = (sden != 0.f) ? 1.f / sden : 0.f;
            }

            float4 xA[2], xB[2], nA[2], nB[2];
            #pragma unroll
            for (int i = 0; i < 2; ++i) {
                const float* src = hdnw + (2 * bl + i) * 512 + q * 8;
                xA[i] = *(const float4*)src;
                xB[i] = *(const float4*)(src + 4);
            }

            float acc_s[4][2], acc_v[2];
            #pragma unroll
            for (int rr = 0; rr < 4; ++rr) { acc_s[rr][0] = 0.f; acc_s[rr][1] = 0.f; }
            acc_v[0] = 0.f; acc_v[1] = 0.f;

            #pragma unroll
            for (int c = 0; c < 8; ++c) {
                if (c < 7) {
                    const int cn = c + 1;
                    #pragma unroll
                    for (int i = 0; i < 2; ++i) {
                        const int b = 2 * bl + i;
                        const float* src = (cn < 4)
                            ? (hdnw + b * 512 + cn * 128 + q * 8)
                            : (paccP + b * 512 + (cn - 4) * 128 + q * 8);
                        float4 a = *(const float4*)src;
                        float4 bq = *(const float4*)(src + 4);
                        if (cn >= 4) {
                            a.x *= inv[i]; a.y *= inv[i]; a.z *= inv[i]; a.w *= inv[i];
                            bq.x *= inv[i]; bq.y *= inv[i]; bq.z *= inv[i]; bq.w *= inv[i];
                        }
                        nA[i] = a; nB[i] = bq;
                    }
                }
                #pragma unroll
                for (int rr = 0; rr < 4; ++rr) {
                    const float* wl = smem + L_WOUT + (rh * 4 + rr) * 1028 + c * 128 + q * 8;
                    float4 w0 = *(const float4*)wl;
                    float4 w1 = *(const float4*)(wl + 4);
                    acc_s[rr][0] += dot4(w0, xA[0]) + dot4(w1, xB[0]);
                    acc_s[rr][1] += dot4(w0, xA[1]) + dot4(w1, xB[1]);
                }
                if (c < 4) {
                    const float* wl = smem + L_WT + rh * 516 + c * 128 + q * 8;
                    float4 w0 = *(const float4*)wl;
                    float4 w1 = *(const float4*)(wl + 4);
                    acc_v[0] += dot4(w0, xA[0]) + dot4(w1, xB[0]);
                    acc_v[1] += dot4(w0, xA[1]) + dot4(w1, xB[1]);
                }
                if (c < 7) {
                    xA[0] = nA[0]; xA[1] = nA[1];
                    xB[0] = nB[0]; xB[1] = nB[1];
                }
            }
            #pragma unroll
            for (int rr = 0; rr < 4; ++rr)
                #pragma unroll
                for (int i = 0; i < 2; ++i) {
                    #pragma unroll
                    for (int off = 1; off < 16; off <<= 1)
                        acc_s[rr][i] += __shfl_xor(acc_s[rr][i], off);
                }
            #pragma unroll
            for (int i = 0; i < 2; ++i) {
                #pragma unroll
                for (int off = 1; off < 16; off <<= 1)
                    acc_v[i] += __shfl_xor(acc_v[i], off);
            }
            // q==0 lanes: write scores/vv, build per-8 partial via rh-merge
            if (q == 0) {
                #pragma unroll
                for (int i = 0; i < 2; ++i) {
                    const int b = 2 * bl + i;
                    float s0 = acc_s[0][i] + bo_r[0];
                    float s1 = acc_s[1][i] + bo_r[1];
                    float s2 = acc_s[2][i] + bo_r[2];
                    float s3 = acc_s[3][i] + bo_r[3];
                    float* sb = scw + b * 2048 + 8 * blk + rh * 4;
                    st2(sb, s0, s1); st2(sb + 2, s2, s3);
                    st1(vvw + b * 512 + 2 * blk + rh, acc_v[i]);
                    float m4 = s0; int i4 = 0;
                    if (s1 > m4) { m4 = s1; i4 = 1; }
                    if (s2 > m4) { m4 = s2; i4 = 2; }
                    if (s3 > m4) { m4 = s3; i4 = 3; }
                    int gidx = 8 * blk + rh * 4 + i4;
                    float se4 = expf(s0 - m4) + expf(s1 - m4)
                              + expf(s2 - m4) + expf(s3 - m4);
                    float mo  = __shfl_xor(m4, 16);
                    float seo = __shfl_xor(se4, 16);
                    int   io  = __shfl_xor(gidx, 16);
                    float M = fmaxf(m4, mo);
                    float se = se4 * expf(m4 - M) + seo * expf(mo - M);
                    int idx = (mo > m4 || (mo == m4 && io < gidx)) ? io : gidx;
                    if (rh == 0) {
                        float* pp = partw + ((size_t)b * 256 + blk) * 4;
                        st2(pp, M, se);
                        st2(pp + 2, (float)idx, 0.f);
                    }
                }
            }
        }
        gridbar(bar, ++bi);

        // ===== P3: flash partial + lse combine + logp + emb =====
        {
            const int fb = blk >> 2, r = blk & 3;
            const int w = tid >> 6, lane = tid & 63;
            const int g = (tid >> 5) & 1, l = tid & 31;

            // stage vv[fb] into padded LDS layout [l*18 + e]
            if (tid < 512)
                smem[L_VVS + (tid >> 4) * 18 + (tid & 15)] = vvw[fb * 512 + tid];
            // lse/argmax combine over 256 partials (wave 15, concurrent)
            if (w == 15) {
                float m = -3.4e38f, se = 0.f; int idx = 0x7fffffff;
                #pragma unroll
                for (int kk = 0; kk < 4; ++kk) {
                    const float* pp = partw + ((size_t)fb * 256 + lane + kk * 64) * 4;
                    float2 a = *(const float2*)pp;
                    float2 ci = *(const float2*)(pp + 2);
                    float M = fmaxf(m, a.x);
                    se = se * expf(m - M) + a.y * expf(a.x - M);
                    int i2 = (int)ci.x;
                    idx = (a.x > m || (a.x == m && i2 < idx)) ? i2 : idx;
                    m = M;
                }
                #pragma unroll
                for (int off = 1; off < 64; off <<= 1) {
                    float mo = __shfl_xor(m, off);
                    float seo = __shfl_xor(se, off);
                    int io = __shfl_xor(idx, off);
                    float M = fmaxf(m, mo);
                    se = se * expf(m - M) + seo * expf(mo - M);
                    idx = (mo > m || (mo == m && io < idx)) ? io : idx;
                    m = M;
                }
                if (lane == 0) {
                    smem[L_LSE] = m + logf(se);
                    smem[L_LSE + 1] = (float)idx;
                }
            }
            __syncthreads();

            // flash: slot = w*2+g (32 slots x 4 rows); l owns 16 floats
            float4 v4[4];
            #pragma unroll
            for (int j = 0; j < 4; ++j)
                v4[j] = *(const float4*)(smem + L_VVS + l * 18 + j * 4);

            float4 a4[4];
            #pragma unroll
            for (int j = 0; j < 4; ++j) a4[j] = make_float4(0.f, 0.f, 0.f, 0.f);
            float s_loc = 0.f;
            const int slot = w * 2 + g;
            #pragma unroll
            for (int p = 0; p < 4; ++p) {
                const int ta = r * 128 + slot * 4 + p;
                const int mk = mask[fb * 512 + ta];
                const float* er = enc + ((size_t)(fb * 512 + ta)) * 512 + l * 16;
                float4 e4[4];
                #pragma unroll
                for (int j = 0; j < 4; ++j) e4[j] = *(const float4*)(er + j * 4);
                float d = dot4(e4[0], v4[0]) + dot4(e4[1], v4[1])
                        + dot4(e4[2], v4[2]) + dot4(e4[3], v4[3]);
                d += __shfl_xor(d, 1);
                d += __shfl_xor(d, 2);
                d += __shfl_xor(d, 4);
                d += __shfl_xor(d, 8);
                d += __shfl_xor(d, 16);
                const float pw = mk ? expf(d) : 0.f;
                s_loc += pw;
                #pragma unroll
                for (int j = 0; j < 4; ++j) {
                    a4[j].x += pw * e4[j].x; a4[j].y += pw * e4[j].y;
                    a4[j].z += pw * e4[j].z; a4[j].w += pw * e4[j].w;
                }
            }
            // combine g-pairs within wave (sum over both slots)
            #pragma unroll
            for (int j = 0; j < 4; ++j) {
                a4[j].x += __shfl_xor(a4[j].x, 32);
                a4[j].y += __shfl_xor(a4[j].y, 32);
                a4[j].z += __shfl_xor(a4[j].z, 32);
                a4[j].w += __shfl_xor(a4[j].w, 32);
            }
            // s_loc is ALREADY uniform across each 32-lane half (d was
            // all-reduced before exp) — only add the two halves. (R6 bug:
            // extra 1..16 shfl reduce inflated it 32x.)
            s_loc += __shfl_xor(s_loc, 32);
            if (g == 0) {
                float* row = smem + L_FA + w * 578 + l * 18;
                *(float4*)(row)      = a4[0];
                *(float4*)(row + 4)  = a4[1];
                *(float4*)(row + 8)  = a4[2];
                *(float4*)(row + 12) = a4[3];
            }
            if (lane == 0) smem[L_SL + w] = s_loc;
            __syncthreads();

            // logp write (needs lse) — 2 cols per thread for tid<256
            const float lse = smem[L_LSE];
            const int amax = (int)smem[L_LSE + 1];
            if (tid < 256) {
                const int c2 = r * 512 + tid * 2;
                float v0 = scw[fb * 2048 + c2]     - lse;
                float v1 = scw[fb * 2048 + c2 + 1] - lse;
                st2(out + ((size_t)(fb * 512 + t)) * 2048 + c2, v0, v1);
            }
            if (r == 0 && tid >= 512 && tid < 576) {
                const int e = tid - 512;
                const float* er = embTab + (size_t)amax * 128 + e * 2;
                st2(embw + fb * 128 + e * 2, er[0], er[1]);
            }

            // column reduce over 16 rowsets -> atomicAdd into pacc/ps
            {
                const int x = tid >> 1, h = tid & 1;
                const int off0 = (x >> 4) * 18 + (x & 15);
                float a = 0.f;
                #pragma unroll
                for (int k = 0; k < 8; ++k)
                    a += smem[L_FA + (h * 8 + k) * 578 + off0];
                a += __shfl_xor(a, 1);
                if (h == 0) atomicAdd(paccC + fb * 512 + x, a);
            }
            if (tid == 0) {
                float s = 0.f;
                #pragma unroll
                for (int k = 0; k < 16; ++k) s += smem[L_SL + k];
                atomicAdd(psC + fb, s);
            }
        }
        gridbar(bar, ++bi);
    }
}

extern "C" void kernel_launch(void* const* d_in, const int* in_sizes, int n_in,
                              void* d_out, int out_size, void* d_ws, size_t ws_size,
                              hipStream_t stream)
{
    const float* enc    = (const float*)d_in[0];
    const int*   mask   = (const int*)  d_in[1];
    const float* embTab = (const float*)d_in[2];
    const float* Wih    = (const float*)d_in[3];
    const float* bih    = (const float*)d_in[4];
    const float* bhh    = (const float*)d_in[5];
    const float* Wa     = (const float*)d_in[6];
    // d_in[7] = b_attn: cancelled by softmax (constant over t)
    const float* Wout   = (const float*)d_in[8];
    const float* bout   = (const float*)d_in[9];
    float* out = (float*)d_out;
    float* wsf = (float*)d_ws;

    (void)hipFuncSetAttribute((const void*)nmt_fused,
                              hipFuncAttributeMaxDynamicSharedMemorySize, 163840);

    // zero barrier state (root, gen, 32 group counters)
    hipMemsetAsync(d_ws, 0, 4352, stream);

    void* args[] = {
        (void*)&enc, (void*)&mask, (void*)&embTab, (void*)&Wih, (void*)&bih,
        (void*)&bhh, (void*)&Wa, (void*)&Wout, (void*)&bout, (void*)&out,
        (void*)&wsf
    };
    hipLaunchCooperativeKernel((void*)nmt_fused, dim3(NBLK), dim3(NTHR),
                               args, (unsigned)(L_TOT * sizeof(float)), stream);
}

// Round 8
// 42772.113 us; speedup vs baseline: 2.0241x; 2.0241x over previous
//
#include <hip/hip_runtime.h>
#include <cstddef>
#include <cstdint>
#include <cmath>

#define NBLK 256
#define NTHR 1024

// ---- dynamic LDS float offsets ----
#define L_WIH   0        // 6 rows x 1156 (pad): s = rh*3+gate, col 2blk+rh
#define L_WOUT  6936     // 8 rows x 1028 (pad): score rows 8blk..8blk+7
#define L_WT    15160    // 2 rows x 516 (pad): W_attn^T rows 2blk,2blk+1
#define L_VVS   16192    // 576: vv staged as [l*18 + e] (32 l-groups of 16)
#define L_LSE   16768    // 2: lse, amax
#define L_SL    16770    // 16: per-wave s_loc partials
#define L_FA    16792    // 16 x 578: flash rowsets [w][l*18+e]
#define L_TOT   26040    // floats = 101.7 KiB

// ---- ws float offsets ----
#define WS_HDN   1088     // [64][512]
#define WS_VV    33856    // [64][512]
#define WS_SC    66624    // [64][2048]
#define WS_PACC  197696   // [2][64][512]
#define WS_PS    263232   // [2][64]
#define WS_EMB   263360   // [64][128]
#define WS_PART  271552   // [64][256][4] {m, se, idxf, pad}

__device__ __forceinline__ float dot4(float4 a, float4 b) {
    return a.x*b.x + a.y*b.y + a.z*b.z + a.w*b.w;
}

// sc1 (agent-scope) stores: visible at the device coherence point.
__device__ __forceinline__ void st1(float* p, float v) {
    __hip_atomic_store(p, v, __ATOMIC_RELAXED, __HIP_MEMORY_SCOPE_AGENT);
}
__device__ __forceinline__ void st2(float* p, float a, float b) {
    union { unsigned long long u; float2 f; } c; c.f = make_float2(a, b);
    __hip_atomic_store((unsigned long long*)p, c.u,
        __ATOMIC_RELAXED, __HIP_MEMORY_SCOPE_AGENT);
}

// Hierarchical grid barrier: 32 groups of 8 -> root -> gen (monotonic,
// relaxed). Exit: ONE agent-scope ACQUIRE per block (thread 0) -> L1/L2
// invalidate covers the whole CU/XCD; other waves are held by syncthreads.
__device__ __forceinline__ void gridbar(unsigned* bar, unsigned iter) {
    asm volatile("s_waitcnt vmcnt(0) lgkmcnt(0)" ::: "memory");
    __syncthreads();
    if (threadIdx.x == 0) {
        const unsigned g = blockIdx.x >> 3;
        unsigned p = __hip_atomic_fetch_add(bar + 64 + g * 32, 1u,
                        __ATOMIC_RELAXED, __HIP_MEMORY_SCOPE_AGENT);
        if (p == iter * 8u - 1u) {
            unsigned rp = __hip_atomic_fetch_add(bar, 1u,
                        __ATOMIC_RELAXED, __HIP_MEMORY_SCOPE_AGENT);
            if (rp == iter * 32u - 1u)
                __hip_atomic_store(bar + 32, iter, __ATOMIC_RELAXED,
                                   __HIP_MEMORY_SCOPE_AGENT);
        }
        while (__hip_atomic_load(bar + 32, __ATOMIC_RELAXED,
                                 __HIP_MEMORY_SCOPE_AGENT) < iter)
            __builtin_amdgcn_s_sleep(1);
        (void)__hip_atomic_load(bar + 32, __ATOMIC_ACQUIRE,
                                __HIP_MEMORY_SCOPE_AGENT);
    }
    __syncthreads();
    asm volatile("" ::: "memory");
}

__global__ __launch_bounds__(NTHR)
__attribute__((amdgpu_waves_per_eu(4, 4)))
void nmt_fused(
    const float* __restrict__ enc, const int* __restrict__ mask,
    const float* __restrict__ embTab, const float* __restrict__ Wih,
    const float* __restrict__ bih, const float* __restrict__ bhh,
    const float* __restrict__ Wa, const float* __restrict__ Wout,
    const float* __restrict__ bout, float* __restrict__ out,
    float* __restrict__ ws)
{
    extern __shared__ float smem[];

    const int blk = blockIdx.x;
    const int tid = threadIdx.x;

    unsigned* bar = (unsigned*)ws;
    float* hdnw = ws + WS_HDN;
    float* vvw  = ws + WS_VV;
    float* scw  = ws + WS_SC;
    float* pacc = ws + WS_PACC;
    float* ps   = ws + WS_PS;
    float* embw = ws + WS_EMB;
    float* partw= ws + WS_PART;

    unsigned bi = 0;

    // ---------------- prologue: weights -> LDS (padded rows) ----------------
    {
        #pragma unroll
        for (int s = 0; s < 6; ++s) {
            const int col = 2 * blk + (s >= 3 ? 1 : 0);
            const int gate = s % 3;
            const int grow = (gate == 0) ? col : (gate == 1) ? 1024 + col : 1536 + col;
            for (int off = tid; off < 1152; off += NTHR)
                smem[L_WIH + s * 1156 + off] = Wih[(size_t)grow * 1152 + off];
        }
        #pragma unroll
        for (int s = 0; s < 8; ++s)
            for (int off = tid; off < 1024; off += NTHR)
                smem[L_WOUT + s * 1028 + off] = Wout[(size_t)(8 * blk + s) * 1024 + off];
        #pragma unroll
        for (int s = 0; s < 2; ++s)
            if (tid < 512)
                smem[L_WT + s * 516 + tid] = Wa[(size_t)tid * 512 + (2 * blk + s)];
    }
    // thread roles (P1/P2)
    const int q  = tid & 15;          // k-split 16
    const int rh = (tid >> 4) & 1;    // row-half
    const int bl = tid >> 5;          // 32 groups x 2 batches

    // P1 biases: col = 2blk + rh
    const int colP1 = 2 * blk + rh;
    const float biB = bih[colP1]        + bhh[colP1];
    const float bgB = bih[1024 + colP1] + bhh[1024 + colP1];
    const float boB = bih[1536 + colP1] + bhh[1536 + colP1];
    // P2 biases: rows 8blk + rh*4 + rr
    float bo_r[4];
    #pragma unroll
    for (int rr = 0; rr < 4; ++rr) bo_r[rr] = bout[8 * blk + rh * 4 + rr];

    // P3 roles + mask bits hoisted to a register (mask is read-only)
    const int fb3 = blk >> 2, r3 = blk & 3;
    const int w3 = tid >> 6, g3 = (tid >> 5) & 1;
    const int slot3 = w3 * 2 + g3;
    int mkbits = 0;
    #pragma unroll
    for (int p = 0; p < 4; ++p)
        mkbits |= (mask[fb3 * 512 + r3 * 128 + slot3 * 4 + p] ? 1 : 0) << p;

    // state init (blocks 0..63): ctx0 -> pacc slot1, ps slot1 = 1, emb = 0
    if (blk < 64) {
        const int b = blk;
        int* ism = (int*)(smem + L_FA);
        ism[tid] = (tid < 512) ? mask[b * 512 + tid] : 0;
        __syncthreads();
        for (int off = 512; off; off >>= 1) {
            if (tid < off) ism[tid] += ism[tid + off];
            __syncthreads();
        }
        int tl = ism[0] - 1;
        if (tl < 0) tl = 0;
        if (tid < 512)
            st1(pacc + 32768 + b * 512 + tid, enc[((size_t)(b * 512 + tl)) * 512 + tid]);
        if (tid == 0) st1(ps + 64 + b, 1.f);
        if (tid < 128) st1(embw + b * 128 + tid, 0.f);
        __syncthreads();
    }
    gridbar(bar, ++bi);

    // ---------------- main loop ----------------
    for (int t = 0; t < 512; ++t) {
        const int cur = t & 1;
        float* paccC = pacc + cur * 32768;
        const float* paccP = pacc + (cur ^ 1) * 32768;
        float* psC = ps + cur * 64;
        const float* psP = ps + (cur ^ 1) * 64;

        // ===== P1: gates GEMM (LDS weights) + LSTM -> hdn =====
        {
            // zero cur-slot accumulators for P3's atomics
            if (tid < 128) st1(paccC + blk * 128 + tid, 0.f);
            if (blk == 0 && tid < 64) st1(psC + tid, 0.f);

            float inv[2];
            #pragma unroll
            for (int i = 0; i < 2; ++i) {
                float sden = psP[2 * bl + i];
                inv[i] = (sden != 0.f) ? 1.f / sden : 0.f;
            }

            float4 xA[2], xB[2], nA[2], nB[2];
            // preload c = 0 (emb)
            #pragma unroll
            for (int i = 0; i < 2; ++i) {
                const float* src = embw + (2 * bl + i) * 128 + q * 8;
                xA[i] = *(const float4*)src;
                xB[i] = *(const float4*)(src + 4);
            }

            float acc[3][2];
            #pragma unroll
            for (int gq = 0; gq < 3; ++gq) { acc[gq][0] = 0.f; acc[gq][1] = 0.f; }

            #pragma unroll
            for (int c = 0; c < 9; ++c) {
                // prefetch c+1
                if (c < 8) {
                    const int cn = c + 1;
                    #pragma unroll
                    for (int i = 0; i < 2; ++i) {
                        const int b = 2 * bl + i;
                        const float* src;
                        if (cn <= 4) src = paccP + b * 512 + (cn - 1) * 128 + q * 8;
                        else         src = enc + ((size_t)(b * 512 + t)) * 512
                                               + (cn - 5) * 128 + q * 8;
                        float4 a = *(const float4*)src;
                        float4 bq = *(const float4*)(src + 4);
                        if (cn <= 4) {
                            a.x *= inv[i]; a.y *= inv[i]; a.z *= inv[i]; a.w *= inv[i];
                            bq.x *= inv[i]; bq.y *= inv[i]; bq.z *= inv[i]; bq.w *= inv[i];
                        }
                        nA[i] = a; nB[i] = bq;
                    }
                }
                // compute c
                #pragma unroll
                for (int gq = 0; gq < 3; ++gq) {
                    const float* wl = smem + L_WIH + (rh * 3 + gq) * 1156 + c * 128 + q * 8;
                    float4 w0 = *(const float4*)wl;
                    float4 w1 = *(const float4*)(wl + 4);
                    acc[gq][0] += dot4(w0, xA[0]) + dot4(w1, xB[0]);
                    acc[gq][1] += dot4(w0, xA[1]) + dot4(w1, xB[1]);
                }
                if (c < 8) {
                    xA[0] = nA[0]; xA[1] = nA[1];
                    xB[0] = nB[0]; xB[1] = nB[1];
                }
            }
            #pragma unroll
            for (int gq = 0; gq < 3; ++gq)
                #pragma unroll
                for (int i = 0; i < 2; ++i) {
                    #pragma unroll
                    for (int off = 1; off < 16; off <<= 1)
                        acc[gq][i] += __shfl_xor(acc[gq][i], off);
                }
            if (q == 0) {
                #pragma unroll
                for (int i = 0; i < 2; ++i) {
                    float ig = acc[0][i] + biB;
                    float gg = acc[1][i] + bgB;
                    float og = acc[2][i] + boB;
                    float cv = (1.f / (1.f + expf(-ig))) * tanhf(gg);
                    float hv = (1.f / (1.f + expf(-og))) * tanhf(cv);
                    st1(hdnw + (2 * bl + i) * 512 + colP1, hv);
                }
            }
        }
        gridbar(bar, ++bi);

        // ===== P2: scores (4 rows/half) + vv (1 row/half) =====
        {
            float inv[2];
            #pragma unroll
            for (int i = 0; i < 2; ++i) {
                float sden = psP[2 * bl + i];
                inv[i] = (sden != 0.f) ? 1.f / sden : 0.f;
            }

            float4 xA[2], xB[2], nA[2], nB[2];
            #pragma unroll
            for (int i = 0; i < 2; ++i) {
                const float* src = hdnw + (2 * bl + i) * 512 + q * 8;
                xA[i] = *(const float4*)src;
                xB[i] = *(const float4*)(src + 4);
            }

            float acc_s[4][2], acc_v[2];
            #pragma unroll
            for (int rr = 0; rr < 4; ++rr) { acc_s[rr][0] = 0.f; acc_s[rr][1] = 0.f; }
            acc_v[0] = 0.f; acc_v[1] = 0.f;

            #pragma unroll
            for (int c = 0; c < 8; ++c) {
                if (c < 7) {
                    const int cn = c + 1;
                    #pragma unroll
                    for (int i = 0; i < 2; ++i) {
                        const int b = 2 * bl + i;
                        const float* src = (cn < 4)
                            ? (hdnw + b * 512 + cn * 128 + q * 8)
                            : (paccP + b * 512 + (cn - 4) * 128 + q * 8);
                        float4 a = *(const float4*)src;
                        float4 bq = *(const float4*)(src + 4);
                        if (cn >= 4) {
                            a.x *= inv[i]; a.y *= inv[i]; a.z *= inv[i]; a.w *= inv[i];
                            bq.x *= inv[i]; bq.y *= inv[i]; bq.z *= inv[i]; bq.w *= inv[i];
                        }
                        nA[i] = a; nB[i] = bq;
                    }
                }
                #pragma unroll
                for (int rr = 0; rr < 4; ++rr) {
                    const float* wl = smem + L_WOUT + (rh * 4 + rr) * 1028 + c * 128 + q * 8;
                    float4 w0 = *(const float4*)wl;
                    float4 w1 = *(const float4*)(wl + 4);
                    acc_s[rr][0] += dot4(w0, xA[0]) + dot4(w1, xB[0]);
                    acc_s[rr][1] += dot4(w0, xA[1]) + dot4(w1, xB[1]);
                }
                if (c < 4) {
                    const float* wl = smem + L_WT + rh * 516 + c * 128 + q * 8;
                    float4 w0 = *(const float4*)wl;
                    float4 w1 = *(const float4*)(wl + 4);
                    acc_v[0] += dot4(w0, xA[0]) + dot4(w1, xB[0]);
                    acc_v[1] += dot4(w0, xA[1]) + dot4(w1, xB[1]);
                }
                if (c < 7) {
                    xA[0] = nA[0]; xA[1] = nA[1];
                    xB[0] = nB[0]; xB[1] = nB[1];
                }
            }
            #pragma unroll
            for (int rr = 0; rr < 4; ++rr)
                #pragma unroll
                for (int i = 0; i < 2; ++i) {
                    #pragma unroll
                    for (int off = 1; off < 16; off <<= 1)
                        acc_s[rr][i] += __shfl_xor(acc_s[rr][i], off);
                }
            #pragma unroll
            for (int i = 0; i < 2; ++i) {
                #pragma unroll
                for (int off = 1; off < 16; off <<= 1)
                    acc_v[i] += __shfl_xor(acc_v[i], off);
            }
            // q==0 lanes: write scores/vv, build per-8 partial via rh-merge
            if (q == 0) {
                #pragma unroll
                for (int i = 0; i < 2; ++i) {
                    const int b = 2 * bl + i;
                    float s0 = acc_s[0][i] + bo_r[0];
                    float s1 = acc_s[1][i] + bo_r[1];
                    float s2 = acc_s[2][i] + bo_r[2];
                    float s3 = acc_s[3][i] + bo_r[3];
                    float* sb = scw + b * 2048 + 8 * blk + rh * 4;
                    st2(sb, s0, s1); st2(sb + 2, s2, s3);
                    st1(vvw + b * 512 + 2 * blk + rh, acc_v[i]);
                    float m4 = s0; int i4 = 0;
                    if (s1 > m4) { m4 = s1; i4 = 1; }
                    if (s2 > m4) { m4 = s2; i4 = 2; }
                    if (s3 > m4) { m4 = s3; i4 = 3; }
                    int gidx = 8 * blk + rh * 4 + i4;
                    float se4 = expf(s0 - m4) + expf(s1 - m4)
                              + expf(s2 - m4) + expf(s3 - m4);
                    float mo  = __shfl_xor(m4, 16);
                    float seo = __shfl_xor(se4, 16);
                    int   io  = __shfl_xor(gidx, 16);
                    float M = fmaxf(m4, mo);
                    float se = se4 * expf(m4 - M) + seo * expf(mo - M);
                    int idx = (mo > m4 || (mo == m4 && io < gidx)) ? io : gidx;
                    if (rh == 0) {
                        float* pp = partw + ((size_t)b * 256 + blk) * 4;
                        st2(pp, M, se);
                        st2(pp + 2, (float)idx, 0.f);
                    }
                }
            }
        }
        gridbar(bar, ++bi);

        // ===== P3: flash partial + lse combine + logp + emb =====
        {
            const int fb = fb3, r = r3;
            const int w = tid >> 6, lane = tid & 63;
            const int g = g3, l = tid & 31;

            // stage vv[fb] into padded LDS layout [l*18 + e]
            if (tid < 512)
                smem[L_VVS + (tid >> 4) * 18 + (tid & 15)] = vvw[fb * 512 + tid];
            // lse/argmax combine over 256 partials (wave 15, concurrent)
            if (w == 15) {
                float m = -3.4e38f, se = 0.f; int idx = 0x7fffffff;
                #pragma unroll
                for (int kk = 0; kk < 4; ++kk) {
                    const float* pp = partw + ((size_t)fb * 256 + lane + kk * 64) * 4;
                    float2 a = *(const float2*)pp;
                    float2 ci = *(const float2*)(pp + 2);
                    float M = fmaxf(m, a.x);
                    se = se * expf(m - M) + a.y * expf(a.x - M);
                    int i2 = (int)ci.x;
                    idx = (a.x > m || (a.x == m && i2 < idx)) ? i2 : idx;
                    m = M;
                }
                #pragma unroll
                for (int off = 1; off < 64; off <<= 1) {
                    float mo = __shfl_xor(m, off);
                    float seo = __shfl_xor(se, off);
                    int io = __shfl_xor(idx, off);
                    float M = fmaxf(m, mo);
                    se = se * expf(m - M) + seo * expf(mo - M);
                    idx = (mo > m || (mo == m && io < idx)) ? io : idx;
                    m = M;
                }
                if (lane == 0) {
                    smem[L_LSE] = m + logf(se);
                    smem[L_LSE + 1] = (float)idx;
                }
            }
            __syncthreads();

            // flash: slot = w*2+g (32 slots x 4 rows); l owns 16 floats
            float4 v4[4];
            #pragma unroll
            for (int j = 0; j < 4; ++j)
                v4[j] = *(const float4*)(smem + L_VVS + l * 18 + j * 4);

            float4 a4[4];
            #pragma unroll
            for (int j = 0; j < 4; ++j) a4[j] = make_float4(0.f, 0.f, 0.f, 0.f);
            float s_loc = 0.f;
            const int slot = slot3;
            #pragma unroll
            for (int p = 0; p < 4; ++p) {
                const int ta = r * 128 + slot * 4 + p;
                const int mk = (mkbits >> p) & 1;
                const float* er = enc + ((size_t)(fb * 512 + ta)) * 512 + l * 16;
                float4 e4[4];
                #pragma unroll
                for (int j = 0; j < 4; ++j) e4[j] = *(const float4*)(er + j * 4);
                float d = dot4(e4[0], v4[0]) + dot4(e4[1], v4[1])
                        + dot4(e4[2], v4[2]) + dot4(e4[3], v4[3]);
                d += __shfl_xor(d, 1);
                d += __shfl_xor(d, 2);
                d += __shfl_xor(d, 4);
                d += __shfl_xor(d, 8);
                d += __shfl_xor(d, 16);
                const float pw = mk ? expf(d) : 0.f;
                s_loc += pw;
                #pragma unroll
                for (int j = 0; j < 4; ++j) {
                    a4[j].x += pw * e4[j].x; a4[j].y += pw * e4[j].y;
                    a4[j].z += pw * e4[j].z; a4[j].w += pw * e4[j].w;
                }
            }
            // combine g-pairs within wave (sum over both slots)
            #pragma unroll
            for (int j = 0; j < 4; ++j) {
                a4[j].x += __shfl_xor(a4[j].x, 32);
                a4[j].y += __shfl_xor(a4[j].y, 32);
                a4[j].z += __shfl_xor(a4[j].z, 32);
                a4[j].w += __shfl_xor(a4[j].w, 32);
            }
            // s_loc is already uniform across each 32-lane half (d was
            // all-reduced before exp) — only add the two halves.
            s_loc += __shfl_xor(s_loc, 32);
            if (g == 0) {
                float* row = smem + L_FA + w * 578 + l * 18;
                *(float4*)(row)      = a4[0];
                *(float4*)(row + 4)  = a4[1];
                *(float4*)(row + 8)  = a4[2];
                *(float4*)(row + 12) = a4[3];
            }
            if (lane == 0) smem[L_SL + w] = s_loc;
            __syncthreads();

            // logp write (needs lse) — 2 cols per thread for tid<256
            const float lse = smem[L_LSE];
            const int amax = (int)smem[L_LSE + 1];
            if (tid < 256) {
                const int c2 = r * 512 + tid * 2;
                float v0 = scw[fb * 2048 + c2]     - lse;
                float v1 = scw[fb * 2048 + c2 + 1] - lse;
                st2(out + ((size_t)(fb * 512 + t)) * 2048 + c2, v0, v1);
            }
            if (r == 0 && tid >= 512 && tid < 576) {
                const int e = tid - 512;
                const float* er = embTab + (size_t)amax * 128 + e * 2;
                st2(embw + fb * 128 + e * 2, er[0], er[1]);
            }

            // column reduce over 16 rowsets -> atomicAdd into pacc/ps
            {
                const int x = tid >> 1, h = tid & 1;
                const int off0 = (x >> 4) * 18 + (x & 15);
                float a = 0.f;
                #pragma unroll
                for (int k = 0; k < 8; ++k)
                    a += smem[L_FA + (h * 8 + k) * 578 + off0];
                a += __shfl_xor(a, 1);
                if (h == 0) atomicAdd(paccC + fb * 512 + x, a);
            }
            if (tid == 0) {
                float s = 0.f;
                #pragma unroll
                for (int k = 0; k < 16; ++k) s += smem[L_SL + k];
                atomicAdd(psC + fb, s);
            }
        }
        gridbar(bar, ++bi);
    }
}

extern "C" void kernel_launch(void* const* d_in, const int* in_sizes, int n_in,
                              void* d_out, int out_size, void* d_ws, size_t ws_size,
                              hipStream_t stream)
{
    const float* enc    = (const float*)d_in[0];
    const int*   mask   = (const int*)  d_in[1];
    const float* embTab = (const float*)d_in[2];
    const float* Wih    = (const float*)d_in[3];
    const float* bih    = (const float*)d_in[4];
    const float* bhh    = (const float*)d_in[5];
    const float* Wa     = (const float*)d_in[6];
    // d_in[7] = b_attn: cancelled by softmax (constant over t)
    const float* Wout   = (const float*)d_in[8];
    const float* bout   = (const float*)d_in[9];
    float* out = (float*)d_out;
    float* wsf = (float*)d_ws;

    (void)hipFuncSetAttribute((const void*)nmt_fused,
                              hipFuncAttributeMaxDynamicSharedMemorySize, 163840);

    // zero barrier state (root, gen, 32 group counters)
    hipMemsetAsync(d_ws, 0, 4352, stream);

    void* args[] = {
        (void*)&enc, (void*)&mask, (void*)&embTab, (void*)&Wih, (void*)&bih,
        (void*)&bhh, (void*)&Wa, (void*)&Wout, (void*)&bout, (void*)&out,
        (void*)&wsf
    };
    hipLaunchCooperativeKernel((void*)nmt_fused, dim3(NBLK), dim3(NTHR),
                               args, (unsigned)(L_TOT * sizeof(float)), stream);
}